// Round 6
// baseline (6531.113 us; speedup 1.0000x reference)
//
#include <hip/hip_runtime.h>
#include <math.h>

#define N_NODES 1024
#define HID 64
#define BATCH 16
#define TSTEPS 288
#define PWIN 24
#define PL 12
#define EMB 16
#define HOR 12

typedef __attribute__((ext_vector_type(4))) short short4_t;
typedef __attribute__((ext_vector_type(8))) short short8_t;
typedef _Float16 f16x8 __attribute__((ext_vector_type(8)));
typedef _Float16 f16x4 __attribute__((ext_vector_type(4)));
typedef float f32x4 __attribute__((ext_vector_type(4)));

__global__ __launch_bounds__(256) void fill_k(float* p, float v, int n) {
    int i = blockIdx.x*256 + threadIdx.x;
    if (i < n) p[i] = v;
}

// block per (ngrp, p): lane = n (coalesced stores), wave wid covers b = 4*wid..+3.
// x[p][j=b*64+h][n] i16, scale per (p,b,n) -> xsc2[((p*16+b)<<10)+n].
__global__ __launch_bounds__(256) void embedq3_k(
    const float* __restrict__ src, const float* __restrict__ vw,
    short* __restrict__ xqT, float* __restrict__ xsc2)
{
    int p = blockIdx.y;
    int n0 = blockIdx.x * 64;
    int t = threadIdx.x;
    int lane = t & 63, wid = t >> 6;
    __shared__ float sv[192][64];     // [b*12+tt][n]
    __shared__ float wvs[PL*HID];
    __shared__ float pe[64];
    for (int r = wid; r < 192; r += 4) {
        int b = r / 12, tt = r - b*12;
        sv[r][lane] = src[((size_t)b*TSTEPS + p*PL + tt)*N_NODES + n0 + lane];
    }
    for (int i = t; i < PL*HID; i += 256) wvs[i] = vw[i];
    if (t < 64) {
        float d = expf(-(float)(t & ~1) * (float)(9.210340371976184/64.0));
        float arg = (float)p * d;
        pe[t] = (t & 1) ? cosf(arg) : sinf(arg);
    }
    __syncthreads();
    float svr[48];
#pragma unroll
    for (int bb = 0; bb < 4; ++bb)
#pragma unroll
        for (int tt = 0; tt < 12; ++tt)
            svr[bb*12 + tt] = sv[(wid*4 + bb)*12 + tt][lane];
#pragma unroll
    for (int bb = 0; bb < 4; ++bb) {
        int b = wid*4 + bb;
        float dots[64];
        float amax = 0.f;
#pragma unroll
        for (int h = 0; h < 64; ++h) {
            float d = pe[h];
#pragma unroll
            for (int tt = 0; tt < 12; ++tt) d += svr[bb*12 + tt] * wvs[tt*HID + h];
            dots[h] = d;
            amax = fmaxf(amax, fabsf(d));
        }
        float inv = (amax > 0.f) ? 32767.f/amax : 0.f;
        short* xp = xqT + ((size_t)p << 20) + (size_t)b*64*1024 + n0 + lane;
#pragma unroll
        for (int h = 0; h < 64; ++h)
            xp[(size_t)h*1024] = (short)__float2int_rn(dots[h]*inv);
        xsc2[((p*16 + b) << 10) + n0 + lane] = (amax > 0.f) ? amax/32767.f : 0.f;
    }
}

// A[n][m] = softmax_m(relu(emb[n]·emb[m])), written as f16 hi/lo pair (compensated)
__global__ __launch_bounds__(256) void adj_k(const float* __restrict__ emb,
    _Float16* __restrict__ Ahi, _Float16* __restrict__ Alo)
{
    __shared__ float en[EMB];
    __shared__ float red[256];
    int n = blockIdx.x, t = threadIdx.x;
    if (t < EMB) en[t] = emb[n*EMB + t];
    __syncthreads();
    float v[4]; float mx = 0.f;
#pragma unroll
    for (int q = 0; q < 4; ++q) {
        int m = q*256 + t;
        float dot = 0.f;
#pragma unroll
        for (int e = 0; e < EMB; ++e) dot += en[e]*emb[m*EMB + e];
        v[q] = fmaxf(dot, 0.f);
        mx = fmaxf(mx, v[q]);
    }
    red[t] = mx; __syncthreads();
    for (int s2 = 128; s2 > 0; s2 >>= 1) {
        if (t < s2) red[t] = fmaxf(red[t], red[t + s2]);
        __syncthreads();
    }
    mx = red[0]; __syncthreads();
    float sum = 0.f;
#pragma unroll
    for (int q = 0; q < 4; ++q) { v[q] = expf(v[q] - mx); sum += v[q]; }
    red[t] = sum; __syncthreads();
    for (int s2 = 128; s2 > 0; s2 >>= 1) {
        if (t < s2) red[t] += red[t + s2];
        __syncthreads();
    }
    float inv = 1.f / red[0];
#pragma unroll
    for (int q = 0; q < 4; ++q) {
        float av = v[q]*inv;
        _Float16 hi = (_Float16)av;
        size_t idx = (size_t)n*N_NODES + q*256 + t;
        Ahi[idx] = hi;
        Alo[idx] = (_Float16)(av - (float)hi);
    }
}

// gwT[e][o][kc] <- gwl[e][kc][o]
template<int OUT>
__global__ __launch_bounds__(256) void wtrans_k(
    const float* __restrict__ gwl, float* __restrict__ gwT)
{
    int idx = blockIdx.x*256 + threadIdx.x;
    int kc = idx & 255;
    int rest = idx >> 8;
    int o = rest % OUT;
    int e = rest / OUT;
    gwT[idx] = gwl[((size_t)e*256 + kc)*OUT + o];
}

// W[n][o][kc] = sum_e emb[n][e]*gwT[e][o][kc], i16 with per-(n,o) row scale.
template<int OUT>
__global__ __launch_bounds__(256) void wnodeq2_k(
    const float* __restrict__ emb, const float* __restrict__ gwT,
    short* __restrict__ WQ, float* __restrict__ wsc)
{
    int t = threadIdx.x;
    int n0 = blockIdx.x * 4;
    int oh = blockIdx.y;
    int lane = t & 63, w = t >> 6;
    __shared__ float se[4][EMB];
    if (t < 4*EMB) se[t >> 4][t & 15] = emb[(n0 + (t >> 4))*EMB + (t & 15)];
    __syncthreads();
    for (int o = oh*(OUT/4) + w; o < (oh+1)*(OUT/4); o += 4) {
        const float* gp = gwT + (size_t)o*256 + lane*4;
        float4 s[4];
#pragma unroll
        for (int ng = 0; ng < 4; ++ng) s[ng] = make_float4(0.f, 0.f, 0.f, 0.f);
#pragma unroll
        for (int e = 0; e < EMB; ++e) {
            float4 g = *(const float4*)(gp + (size_t)e*(OUT*256));
#pragma unroll
            for (int ng = 0; ng < 4; ++ng) {
                float c = se[ng][e];
                s[ng].x += c*g.x; s[ng].y += c*g.y; s[ng].z += c*g.z; s[ng].w += c*g.w;
            }
        }
#pragma unroll
        for (int ng = 0; ng < 4; ++ng) {
            float amax = fmaxf(fmaxf(fabsf(s[ng].x), fabsf(s[ng].y)),
                               fmaxf(fabsf(s[ng].z), fabsf(s[ng].w)));
#pragma unroll
            for (int d = 32; d > 0; d >>= 1) amax = fmaxf(amax, __shfl_xor(amax, d));
            float inv = (amax > 0.f) ? 32767.f/amax : 0.f;
            short4_t q;
            q.x = (short)__float2int_rn(s[ng].x*inv);
            q.y = (short)__float2int_rn(s[ng].y*inv);
            q.z = (short)__float2int_rn(s[ng].z*inv);
            q.w = (short)__float2int_rn(s[ng].w*inv);
            *(short4_t*)(WQ + ((size_t)(n0+ng)*OUT + o)*256 + lane*4) = q;
            if (lane == 0) wsc[(n0+ng)*OUT + o] = (amax > 0.f) ? amax/32767.f : 0.f;
        }
    }
}

__global__ __launch_bounds__(256) void bias_k(const float* __restrict__ emb,
                        const float* __restrict__ gbl, float* __restrict__ bn, int OUT)
{
    int idx = blockIdx.x*256 + threadIdx.x;
    if (idx >= N_NODES*OUT) return;
    int n = idx / OUT, o = idx % OUT;
    float s = 0.f;
#pragma unroll
    for (int e = 0; e < EMB; ++e) s += emb[n*EMB + e]*gbl[e*OUT + o];
    bn[idx] = s;
}

// C = A@B via mfma_f32_16x16x32_f16, f32-emulated (Ahi/Alo precomputed; B split
// hi/lo in staging; acc = Al*Bh + Ah*Bl + Ah*Bh). All jobs split-K=2 (ks halves
// written to out + ks*1M; consumers sum the pair). B operands TRANSPOSED [j][m]:
//   job 0: B = hT  f32              -> pAh
//   job 1: B = xqT i16 * xsc2[b][m] -> pAx
//   job 2: B = zhT f32              -> pAzh
// z = zoff + blockIdx.z in 0..5: job = z>>1, ks = z&1.
__global__ __launch_bounds__(256) void gemm16_k(
    const _Float16* __restrict__ Ahi, const _Float16* __restrict__ Alo,
    const float* __restrict__ hT, const short* __restrict__ xqTp,
    const float* __restrict__ xscp, const float* __restrict__ zhT,
    float* __restrict__ pAh, float* __restrict__ pAx, float* __restrict__ pAzh,
    int zoff)
{
    int z = zoff + blockIdx.z;
    int job = z >> 1, ks = z & 1;
    int kbase = ks << 9;
    float* out = ((job == 0) ? pAh : (job == 1) ? pAx : pAzh) + ((size_t)ks << 20);
    const float* BTf = (job == 0) ? hT : zhT;
    __shared__ _Float16 Ash[64*72];
    __shared__ _Float16 Asl[64*72];
    __shared__ _Float16 Bsh[64*72];
    __shared__ _Float16 Bsl[64*72];
    int t = threadIdx.x;
    int l = t & 63, w = t >> 6;
    int wr = w >> 1, wc = w & 1;
    int r0 = blockIdx.y*64, c0 = blockIdx.x*64;
    f32x4 acc[2][2];
#pragma unroll
    for (int i = 0; i < 2; ++i)
#pragma unroll
        for (int j = 0; j < 2; ++j) acc[i][j] = (f32x4){0.f,0.f,0.f,0.f};
    int arow = wr*32 + (l & 15);
    int brow = wc*32 + (l & 15);
    int koff = (l >> 4)*8;
    const float* sbase = xscp + ((c0 >> 6) << 10);   // per-(b,n) x scales, b = c0/64
    for (int k0 = kbase; k0 < kbase + 512; k0 += 64) {
        __syncthreads();
        // A tiles: coalesced f16x8
#pragma unroll
        for (int c = 0; c < 2; ++c) {
            int id = t + 256*c;
            int row = id >> 3, k8 = id & 7;
            *(f16x8*)(&Ash[row*72 + k8*8]) =
                *(const f16x8*)(&Ahi[(size_t)(r0+row)*1024 + k0 + k8*8]);
            *(f16x8*)(&Asl[row*72 + k8*8]) =
                *(const f16x8*)(&Alo[(size_t)(r0+row)*1024 + k0 + k8*8]);
        }
        // B tile from transposed source, coalesced along m
        if (job == 1) {
#pragma unroll
            for (int c = 0; c < 2; ++c) {
                int id = t + 256*c;
                int row = id >> 3, k8 = id & 7;
                short8_t q8 = *(const short8_t*)(xqTp + (size_t)(c0+row)*1024 + k0 + k8*8);
                float4 s0 = *(const float4*)(sbase + k0 + k8*8);
                float4 s1 = *(const float4*)(sbase + k0 + k8*8 + 4);
                float vv[8];
                vv[0] = (float)q8[0]*s0.x; vv[1] = (float)q8[1]*s0.y;
                vv[2] = (float)q8[2]*s0.z; vv[3] = (float)q8[3]*s0.w;
                vv[4] = (float)q8[4]*s1.x; vv[5] = (float)q8[5]*s1.y;
                vv[6] = (float)q8[6]*s1.z; vv[7] = (float)q8[7]*s1.w;
                f16x8 hi, lo;
#pragma unroll
                for (int i = 0; i < 8; ++i) {
                    _Float16 h = (_Float16)vv[i];
                    hi[i] = h;
                    lo[i] = (_Float16)(vv[i] - (float)h);
                }
                *(f16x8*)(&Bsh[row*72 + k8*8]) = hi;
                *(f16x8*)(&Bsl[row*72 + k8*8]) = lo;
            }
        } else {
#pragma unroll
            for (int c = 0; c < 4; ++c) {
                int id = t + 256*c;
                int row = id >> 4, kq = id & 15;
                float4 v = *(const float4*)(&BTf[(size_t)(c0+row)*1024 + k0 + kq*4]);
                float vv[4] = {v.x, v.y, v.z, v.w};
                f16x4 hi, lo;
#pragma unroll
                for (int i = 0; i < 4; ++i) {
                    _Float16 h = (_Float16)vv[i];
                    hi[i] = h;
                    lo[i] = (_Float16)(vv[i] - (float)h);
                }
                *(f16x4*)(&Bsh[row*72 + kq*4]) = hi;
                *(f16x4*)(&Bsl[row*72 + kq*4]) = lo;
            }
        }
        __syncthreads();
#pragma unroll
        for (int kk = 0; kk < 2; ++kk) {
            int ko = kk*32 + koff;
            f16x8 ah0 = *(const f16x8*)(&Ash[(size_t)arow*72 + ko]);
            f16x8 ah1 = *(const f16x8*)(&Ash[(size_t)(arow+16)*72 + ko]);
            f16x8 al0 = *(const f16x8*)(&Asl[(size_t)arow*72 + ko]);
            f16x8 al1 = *(const f16x8*)(&Asl[(size_t)(arow+16)*72 + ko]);
            f16x8 bh0 = *(const f16x8*)(&Bsh[(size_t)brow*72 + ko]);
            f16x8 bh1 = *(const f16x8*)(&Bsh[(size_t)(brow+16)*72 + ko]);
            f16x8 bl0 = *(const f16x8*)(&Bsl[(size_t)brow*72 + ko]);
            f16x8 bl1 = *(const f16x8*)(&Bsl[(size_t)(brow+16)*72 + ko]);
            acc[0][0] = __builtin_amdgcn_mfma_f32_16x16x32_f16(al0, bh0, acc[0][0], 0, 0, 0);
            acc[0][0] = __builtin_amdgcn_mfma_f32_16x16x32_f16(ah0, bl0, acc[0][0], 0, 0, 0);
            acc[0][0] = __builtin_amdgcn_mfma_f32_16x16x32_f16(ah0, bh0, acc[0][0], 0, 0, 0);
            acc[0][1] = __builtin_amdgcn_mfma_f32_16x16x32_f16(al0, bh1, acc[0][1], 0, 0, 0);
            acc[0][1] = __builtin_amdgcn_mfma_f32_16x16x32_f16(ah0, bl1, acc[0][1], 0, 0, 0);
            acc[0][1] = __builtin_amdgcn_mfma_f32_16x16x32_f16(ah0, bh1, acc[0][1], 0, 0, 0);
            acc[1][0] = __builtin_amdgcn_mfma_f32_16x16x32_f16(al1, bh0, acc[1][0], 0, 0, 0);
            acc[1][0] = __builtin_amdgcn_mfma_f32_16x16x32_f16(ah1, bl0, acc[1][0], 0, 0, 0);
            acc[1][0] = __builtin_amdgcn_mfma_f32_16x16x32_f16(ah1, bh0, acc[1][0], 0, 0, 0);
            acc[1][1] = __builtin_amdgcn_mfma_f32_16x16x32_f16(al1, bh1, acc[1][1], 0, 0, 0);
            acc[1][1] = __builtin_amdgcn_mfma_f32_16x16x32_f16(ah1, bl1, acc[1][1], 0, 0, 0);
            acc[1][1] = __builtin_amdgcn_mfma_f32_16x16x32_f16(ah1, bh1, acc[1][1], 0, 0, 0);
        }
    }
    // C/D layout: col = lane&15, row = 4*(lane>>4)+reg  [measured m89/m91]
#pragma unroll
    for (int fr = 0; fr < 2; ++fr)
#pragma unroll
        for (int fc = 0; fc < 2; ++fc) {
            int orow = r0 + wr*32 + fr*16 + ((l >> 4) << 2);
            int ocol = c0 + wc*32 + fc*16 + (l & 15);
#pragma unroll
            for (int i = 0; i < 4; ++i)
                out[(size_t)(orow+i)*1024 + ocol] = acc[fr][fc][i];
        }
}

// zr[n][b][o] = sigmoid([x,h,Ax,Ah]·Wq[n](o,:)·ws + bg); writes zhT[j][n]=z*h.
// blockIdx XCD-swizzled so consecutive-n blocks share an XCD (scatter-write locality).
template<int FIRST>
__global__ __launch_bounds__(256) void gate_k(
    const short* __restrict__ xqTp, const float* __restrict__ xscp,
    const float* __restrict__ hst, const float* __restrict__ pAx,
    const float* __restrict__ pAh, const short* __restrict__ WQ,
    const float* __restrict__ wsc, const float* __restrict__ bg,
    float* __restrict__ zr, float* __restrict__ zhT)
{
    __shared__ float inp[16*256];
    int n = ((blockIdx.x & 7) << 7) | (blockIdx.x >> 3);
    int t = threadIdx.x;
    size_t nb = (size_t)n*1024;
    for (int i = t; i < 1024; i += 256) {
        int b = i >> 6, c = i & 63;
        float sx = xscp[(b << 10) + n];
        inp[b*256 + c]       = (float)xqTp[(size_t)i*1024 + n] * sx;
        inp[b*256 + 64 + c]  = FIRST ? 0.f : hst[nb + i];
        inp[b*256 + 128 + c] = pAx[nb + i] + pAx[nb + i + 1048576];
        inp[b*256 + 192 + c] = FIRST ? 0.f : (pAh[nb + i] + pAh[nb + i + 1048576]);
    }
    __syncthreads();
    int o = t & 127, g = t >> 7;
    const short* wp = WQ + ((size_t)n*128 + o)*256;
    float ws = wsc[n*128 + o];
    float bias = bg[n*128 + o];
    float acc[8];
#pragma unroll
    for (int u = 0; u < 8; ++u) acc[u] = 0.f;
    for (int k0 = 0; k0 < 256; k0 += 4) {
        short4_t w4 = *(const short4_t*)(wp + k0);
        float w0 = (float)w4.x, w1 = (float)w4.y, w2 = (float)w4.z, w3 = (float)w4.w;
#pragma unroll
        for (int u = 0; u < 8; ++u) {
            float4 iv = *(const float4*)(&inp[(g*8 + u)*256 + k0]);
            acc[u] += w0*iv.x + w1*iv.y + w2*iv.z + w3*iv.w;
        }
    }
#pragma unroll
    for (int u = 0; u < 8; ++u) {
        int b = g*8 + u;
        float pre = acc[u]*ws + bias;
        float val = 1.f/(1.f + expf(-pre));
        zr[((size_t)n*16 + b)*128 + o] = val;
        if (!FIRST && o < 64)
            zhT[(size_t)(b*64 + o)*1024 + n] = val * inp[b*256 + 64 + o];
    }
}

// h_new = r*h + (1-r)*tanh([x, z*h, Ax, Azh]·Wu[n]·ws + bu); writes hst rows,
// hT columns, (WX) next-layer xqT i16 columns. XCD-swizzled blockIdx.
template<int FIRST, int WX>
__global__ __launch_bounds__(256) void upd_k(
    short* __restrict__ xqTp, const float* __restrict__ xscp,
    float* __restrict__ hst, const float* __restrict__ pAx,
    const float* __restrict__ pAzh, const float* __restrict__ zr,
    const short* __restrict__ WQ, const float* __restrict__ wsc,
    const float* __restrict__ bu, float* __restrict__ hT)
{
    __shared__ float inp[16*256];
    int n = ((blockIdx.x & 7) << 7) | (blockIdx.x >> 3);
    int t = threadIdx.x;
    size_t nb = (size_t)n*1024;
    for (int i = t; i < 1024; i += 256) {
        int b = i >> 6, c = i & 63;
        float sx = xscp[(b << 10) + n];
        float hv = FIRST ? 0.f : hst[nb + i];
        float zv = zr[((size_t)n*16 + b)*128 + c];
        inp[b*256 + c]       = (float)xqTp[(size_t)i*1024 + n] * sx;
        inp[b*256 + 64 + c]  = zv * hv;
        inp[b*256 + 128 + c] = pAx[nb + i] + pAx[nb + i + 1048576];
        inp[b*256 + 192 + c] = FIRST ? 0.f : (pAzh[nb + i] + pAzh[nb + i + 1048576]);
    }
    __syncthreads();
    int o = t & 63, g = t >> 6;
    const short* wp = WQ + ((size_t)n*64 + o)*256;
    float ws = wsc[n*64 + o];
    float bias = bu[n*64 + o];
    float acc[4];
#pragma unroll
    for (int u = 0; u < 4; ++u) acc[u] = 0.f;
    for (int k0 = 0; k0 < 256; k0 += 4) {
        short4_t w4 = *(const short4_t*)(wp + k0);
        float w0 = (float)w4.x, w1 = (float)w4.y, w2 = (float)w4.z, w3 = (float)w4.w;
#pragma unroll
        for (int u = 0; u < 4; ++u) {
            float4 iv = *(const float4*)(&inp[(g*4 + u)*256 + k0]);
            acc[u] += w0*iv.x + w1*iv.y + w2*iv.z + w3*iv.w;
        }
    }
#pragma unroll
    for (int u = 0; u < 4; ++u) {
        int b = g*4 + u;
        float r = zr[((size_t)n*16 + b)*128 + 64 + o];
        float hold = FIRST ? 0.f : hst[nb + b*64 + o];
        float hc = tanhf(acc[u]*ws + bias);
        float hn = r*hold + (1.f - r)*hc;
        hst[nb + b*64 + o] = hn;
        hT[(size_t)(b*64 + o)*1024 + n] = hn;
        if (WX) xqTp[(size_t)(b*64 + o)*1024 + n] = (short)__float2int_rn(hn*32767.f);
    }
}

// out[b][o][n] = h[n][b][:]·ecw[o][:] + ecb[o]
__global__ __launch_bounds__(256) void endconv_k(
    const float* __restrict__ hst, const float* __restrict__ ecw,
    const float* __restrict__ ecb, float* __restrict__ out)
{
    int idx = blockIdx.x*256 + threadIdx.x;
    int n = idx & 1023;
    int o = (idx >> 10) % HOR;
    int b = idx / (HOR*1024);
    float s = ecb[o];
#pragma unroll
    for (int hh = 0; hh < 64; ++hh)
        s += hst[((size_t)n*16 + b)*64 + hh] * ecw[o*64 + hh];
    out[idx] = s;
}

extern "C" void kernel_launch(void* const* d_in, const int* in_sizes, int n_in,
                              void* d_out, int out_size, void* d_ws, size_t ws_size,
                              hipStream_t stream)
{
    const float* source = (const float*)d_in[0];
    const float* emb    = (const float*)d_in[2];
    const float* vw     = (const float*)d_in[3];
    const float* gate_w = (const float*)d_in[4];
    const float* gate_b = (const float*)d_in[5];
    const float* upd_w  = (const float*)d_in[6];
    const float* upd_b  = (const float*)d_in[7];
    const float* ecw    = (const float*)d_in[8];
    const float* ecb    = (const float*)d_in[9];
    float* out = (float*)d_out;

    // ---- workspace carve: ~197 MB ----
    char* p = (char*)d_ws;
    _Float16* Ahi = (_Float16*)p; p += (size_t)1048576*2;    //   2.0 MB
    _Float16* Alo = (_Float16*)p; p += (size_t)1048576*2;    //   2.0 MB
    short* WgQ  = (short*)p;  p += (size_t)33554432*2;       //  64.0 MB
    short* WuQ  = (short*)p;  p += (size_t)16777216*2;       //  32.0 MB
    float* swg  = (float*)p;  p += (size_t)131072*4;         //   0.5 MB
    float* swu  = (float*)p;  p += (size_t)65536*4;          //   0.25 MB
    float* bgn  = (float*)p;  p += (size_t)131072*4;         //   0.5 MB
    float* bun  = (float*)p;  p += (size_t)65536*4;          //   0.25 MB
    short* xqT  = (short*)p;  p += (size_t)25165824*2;       //  48.0 MB  [p][j][n] i16
    float* xscA = (float*)p;  p += (size_t)393216*4;         //   1.5 MB  layer-0 scales [p][b][n]
    float* xscB = (float*)p;  p += (size_t)393216*4;         //   1.5 MB  layer-1 scales (const)
    float* hbuf = (float*)p;  p += (size_t)1048576*4;        //   4.0 MB  h rows [n][j]
    float* hT   = (float*)p;  p += (size_t)1048576*4;        //   4.0 MB  h cols [j][n]
    float* zrb  = (float*)p;  p += (size_t)2097152*4;        //   8.0 MB
    float* zhT  = (float*)p;  p += (size_t)1048576*4;        //   4.0 MB  (z*h)^T
    float* pAh  = (float*)p;  p += (size_t)2097152*4;        //   8.0 MB  split-K pair
    float* pAx  = (float*)p;  p += (size_t)2097152*4;        //   8.0 MB  split-K pair
    float* pAzh = (float*)p;  p += (size_t)2097152*4;        //   8.0 MB  split-K pair
    float* gwT  = pAzh;   // 2 MB scratch, aliases pAzh (dead during layer setup)

    embedq3_k<<<dim3(16,24), 256, 0, stream>>>(source, vw, xqT, xscA);
    adj_k<<<1024, 256, 0, stream>>>(emb, Ahi, Alo);
    fill_k<<<1536, 256, 0, stream>>>(xscB, 1.f/32767.f, 393216);

    for (int l = 0; l < 2; ++l) {
        const float* xsc2 = (l == 0) ? xscA : xscB;
        wtrans_k<128><<<2048, 256, 0, stream>>>(gate_w + (size_t)l*524288, gwT);
        wnodeq2_k<128><<<dim3(256,4), 256, 0, stream>>>(emb, gwT, WgQ, swg);
        wtrans_k<64><<<1024, 256, 0, stream>>>(upd_w + (size_t)l*262144, gwT);
        wnodeq2_k<64><<<dim3(256,4), 256, 0, stream>>>(emb, gwT, WuQ, swu);
        bias_k<<<512, 256, 0, stream>>>(emb, gate_b + l*2048, bgn, 128);
        bias_k<<<256, 256, 0, stream>>>(emb, upd_b + l*1024, bun, 64);
        for (int ps = 0; ps < PWIN; ++ps) {
            short* xqT_p = xqT + ((size_t)ps << 20);
            const float* xsc_p = xsc2 + (size_t)ps*16384;
            if (ps == 0) {
                // h == 0: only A@x needed (job 1, both K-halves)
                gemm16_k<<<dim3(16,16,2), 256, 0, stream>>>(Ahi, Alo, hT, xqT_p, xsc_p, zhT, pAh, pAx, pAzh, 2);
                gate_k<1><<<1024, 256, 0, stream>>>(xqT_p, xsc_p, hbuf, pAx, pAh, WgQ, swg, bgn, zrb, zhT);
                if (l == 0)
                    upd_k<1,1><<<1024, 256, 0, stream>>>(xqT_p, xsc_p, hbuf, pAx, pAzh, zrb, WuQ, swu, bun, hT);
                else
                    upd_k<1,0><<<1024, 256, 0, stream>>>(xqT_p, xsc_p, hbuf, pAx, pAzh, zrb, WuQ, swu, bun, hT);
            } else {
                gemm16_k<<<dim3(16,16,4), 256, 0, stream>>>(Ahi, Alo, hT, xqT_p, xsc_p, zhT, pAh, pAx, pAzh, 0);
                gate_k<0><<<1024, 256, 0, stream>>>(xqT_p, xsc_p, hbuf, pAx, pAh, WgQ, swg, bgn, zrb, zhT);
                gemm16_k<<<dim3(16,16,2), 256, 0, stream>>>(Ahi, Alo, hT, xqT_p, xsc_p, zhT, pAh, pAx, pAzh, 4);
                if (l == 0)
                    upd_k<0,1><<<1024, 256, 0, stream>>>(xqT_p, xsc_p, hbuf, pAx, pAzh, zrb, WuQ, swu, bun, hT);
                else
                    upd_k<0,0><<<1024, 256, 0, stream>>>(xqT_p, xsc_p, hbuf, pAx, pAzh, zrb, WuQ, swu, bun, hT);
            }
        }
    }
    endconv_k<<<768, 256, 0, stream>>>(hbuf, ecw, ecb, out);
}

// Round 7
// 5393.168 us; speedup vs baseline: 1.2110x; 1.2110x over previous
//
#include <hip/hip_runtime.h>
#include <math.h>

#define N_NODES 1024
#define HID 64
#define BATCH 16
#define TSTEPS 288
#define PWIN 24
#define PL 12
#define EMB 16
#define HOR 12

typedef __attribute__((ext_vector_type(4))) short short4_t;
typedef __attribute__((ext_vector_type(8))) short short8_t;
typedef _Float16 f16x8 __attribute__((ext_vector_type(8)));
typedef _Float16 f16x4 __attribute__((ext_vector_type(4)));
typedef float f32x4 __attribute__((ext_vector_type(4)));

__global__ __launch_bounds__(256) void fill_k(float* p, float v, int n) {
    int i = blockIdx.x*256 + threadIdx.x;
    if (i < n) p[i] = v;
}

// block per (ngrp, p): lane = n (coalesced stores), wave wid covers b = 4*wid..+3.
// Two-pass per b (amax pass, quantize pass) with 8-wide register chunks — no
// dots[64] array, no spill (R6 post-mortem: VGPR=256 + 1.1 GB scratch traffic).
// x[p][j=b*64+h][n] i16, scale per (p,b,n) -> xsc2[((p*16+b)<<10)+n].
__global__ __launch_bounds__(256) void embedq4_k(
    const float* __restrict__ src, const float* __restrict__ vw,
    short* __restrict__ xqT, float* __restrict__ xsc2)
{
    int p = blockIdx.y;
    int n0 = blockIdx.x * 64;
    int t = threadIdx.x;
    int lane = t & 63, wid = t >> 6;
    __shared__ float sv[192][64];     // [b*12+tt][n]
    __shared__ float wvs[PL*HID];
    __shared__ float pe[64];
    for (int r = wid; r < 192; r += 4) {
        int b = r / 12, tt = r - b*12;
        sv[r][lane] = src[((size_t)b*TSTEPS + p*PL + tt)*N_NODES + n0 + lane];
    }
    for (int i = t; i < PL*HID; i += 256) wvs[i] = vw[i];
    if (t < 64) {
        float d = expf(-(float)(t & ~1) * (float)(9.210340371976184/64.0));
        float arg = (float)p * d;
        pe[t] = (t & 1) ? cosf(arg) : sinf(arg);
    }
    __syncthreads();
#pragma unroll 1
    for (int bb = 0; bb < 4; ++bb) {
        int b = wid*4 + bb;
        float svr[12];
#pragma unroll
        for (int tt = 0; tt < 12; ++tt) svr[tt] = sv[b*12 + tt][lane];
        float amax = 0.f;
#pragma unroll 1
        for (int h0 = 0; h0 < 64; h0 += 8) {
#pragma unroll
            for (int hh = 0; hh < 8; ++hh) {
                int h = h0 + hh;
                float d = pe[h];
#pragma unroll
                for (int tt = 0; tt < 12; ++tt) d += svr[tt] * wvs[tt*HID + h];
                amax = fmaxf(amax, fabsf(d));
            }
        }
        float inv = (amax > 0.f) ? 32767.f/amax : 0.f;
        short* xp = xqT + ((size_t)p << 20) + (size_t)b*64*1024 + n0 + lane;
#pragma unroll 1
        for (int h0 = 0; h0 < 64; h0 += 8) {
#pragma unroll
            for (int hh = 0; hh < 8; ++hh) {
                int h = h0 + hh;
                float d = pe[h];
#pragma unroll
                for (int tt = 0; tt < 12; ++tt) d += svr[tt] * wvs[tt*HID + h];
                xp[(size_t)h*1024] = (short)__float2int_rn(d*inv);
            }
        }
        xsc2[((p*16 + b) << 10) + n0 + lane] = (amax > 0.f) ? amax/32767.f : 0.f;
    }
}

// A[n][m] = softmax_m(relu(emb[n]·emb[m])), written as f16 hi/lo pair (compensated)
__global__ __launch_bounds__(256) void adj_k(const float* __restrict__ emb,
    _Float16* __restrict__ Ahi, _Float16* __restrict__ Alo)
{
    __shared__ float en[EMB];
    __shared__ float red[256];
    int n = blockIdx.x, t = threadIdx.x;
    if (t < EMB) en[t] = emb[n*EMB + t];
    __syncthreads();
    float v[4]; float mx = 0.f;
#pragma unroll
    for (int q = 0; q < 4; ++q) {
        int m = q*256 + t;
        float dot = 0.f;
#pragma unroll
        for (int e = 0; e < EMB; ++e) dot += en[e]*emb[m*EMB + e];
        v[q] = fmaxf(dot, 0.f);
        mx = fmaxf(mx, v[q]);
    }
    red[t] = mx; __syncthreads();
    for (int s2 = 128; s2 > 0; s2 >>= 1) {
        if (t < s2) red[t] = fmaxf(red[t], red[t + s2]);
        __syncthreads();
    }
    mx = red[0]; __syncthreads();
    float sum = 0.f;
#pragma unroll
    for (int q = 0; q < 4; ++q) { v[q] = expf(v[q] - mx); sum += v[q]; }
    red[t] = sum; __syncthreads();
    for (int s2 = 128; s2 > 0; s2 >>= 1) {
        if (t < s2) red[t] += red[t + s2];
        __syncthreads();
    }
    float inv = 1.f / red[0];
#pragma unroll
    for (int q = 0; q < 4; ++q) {
        float av = v[q]*inv;
        _Float16 hi = (_Float16)av;
        size_t idx = (size_t)n*N_NODES + q*256 + t;
        Ahi[idx] = hi;
        Alo[idx] = (_Float16)(av - (float)hi);
    }
}

// gwT[e][o][kc] <- gwl[e][kc][o]
template<int OUT>
__global__ __launch_bounds__(256) void wtrans_k(
    const float* __restrict__ gwl, float* __restrict__ gwT)
{
    int idx = blockIdx.x*256 + threadIdx.x;
    int kc = idx & 255;
    int rest = idx >> 8;
    int o = rest % OUT;
    int e = rest / OUT;
    gwT[idx] = gwl[((size_t)e*256 + kc)*OUT + o];
}

// W[n][o][kc] = sum_e emb[n][e]*gwT[e][o][kc], i16 with per-(n,o) row scale.
template<int OUT>
__global__ __launch_bounds__(256) void wnodeq2_k(
    const float* __restrict__ emb, const float* __restrict__ gwT,
    short* __restrict__ WQ, float* __restrict__ wsc)
{
    int t = threadIdx.x;
    int n0 = blockIdx.x * 4;
    int oh = blockIdx.y;
    int lane = t & 63, w = t >> 6;
    __shared__ float se[4][EMB];
    if (t < 4*EMB) se[t >> 4][t & 15] = emb[(n0 + (t >> 4))*EMB + (t & 15)];
    __syncthreads();
    for (int o = oh*(OUT/4) + w; o < (oh+1)*(OUT/4); o += 4) {
        const float* gp = gwT + (size_t)o*256 + lane*4;
        float4 s[4];
#pragma unroll
        for (int ng = 0; ng < 4; ++ng) s[ng] = make_float4(0.f, 0.f, 0.f, 0.f);
#pragma unroll
        for (int e = 0; e < EMB; ++e) {
            float4 g = *(const float4*)(gp + (size_t)e*(OUT*256));
#pragma unroll
            for (int ng = 0; ng < 4; ++ng) {
                float c = se[ng][e];
                s[ng].x += c*g.x; s[ng].y += c*g.y; s[ng].z += c*g.z; s[ng].w += c*g.w;
            }
        }
#pragma unroll
        for (int ng = 0; ng < 4; ++ng) {
            float amax = fmaxf(fmaxf(fabsf(s[ng].x), fabsf(s[ng].y)),
                               fmaxf(fabsf(s[ng].z), fabsf(s[ng].w)));
#pragma unroll
            for (int d = 32; d > 0; d >>= 1) amax = fmaxf(amax, __shfl_xor(amax, d));
            float inv = (amax > 0.f) ? 32767.f/amax : 0.f;
            short4_t q;
            q.x = (short)__float2int_rn(s[ng].x*inv);
            q.y = (short)__float2int_rn(s[ng].y*inv);
            q.z = (short)__float2int_rn(s[ng].z*inv);
            q.w = (short)__float2int_rn(s[ng].w*inv);
            *(short4_t*)(WQ + ((size_t)(n0+ng)*OUT + o)*256 + lane*4) = q;
            if (lane == 0) wsc[(n0+ng)*OUT + o] = (amax > 0.f) ? amax/32767.f : 0.f;
        }
    }
}

__global__ __launch_bounds__(256) void bias_k(const float* __restrict__ emb,
                        const float* __restrict__ gbl, float* __restrict__ bn, int OUT)
{
    int idx = blockIdx.x*256 + threadIdx.x;
    if (idx >= N_NODES*OUT) return;
    int n = idx / OUT, o = idx % OUT;
    float s = 0.f;
#pragma unroll
    for (int e = 0; e < EMB; ++e) s += emb[n*EMB + e]*gbl[e*OUT + o];
    bn[idx] = s;
}

// C = A@B via mfma_f32_16x16x32_f16, f32-emulated (Ahi/Alo precomputed; B split
// hi/lo in staging; acc = Al*Bh + Ah*Bl + Ah*Bh). All jobs split-K=2 (ks halves
// written to out + ks*1M; consumers sum the pair). B operands TRANSPOSED [j][m]:
//   job 0: B = hT  f32              -> pAh
//   job 1: B = xqT i16 * xsc2[b][m] -> pAx
//   job 2: B = zhT f32              -> pAzh
// z = zoff + blockIdx.z in 0..5: job = z>>1, ks = z&1.
__global__ __launch_bounds__(256) void gemm16_k(
    const _Float16* __restrict__ Ahi, const _Float16* __restrict__ Alo,
    const float* __restrict__ hT, const short* __restrict__ xqTp,
    const float* __restrict__ xscp, const float* __restrict__ zhT,
    float* __restrict__ pAh, float* __restrict__ pAx, float* __restrict__ pAzh,
    int zoff)
{
    int z = zoff + blockIdx.z;
    int job = z >> 1, ks = z & 1;
    int kbase = ks << 9;
    float* out = ((job == 0) ? pAh : (job == 1) ? pAx : pAzh) + ((size_t)ks << 20);
    const float* BTf = (job == 0) ? hT : zhT;
    __shared__ _Float16 Ash[64*72];
    __shared__ _Float16 Asl[64*72];
    __shared__ _Float16 Bsh[64*72];
    __shared__ _Float16 Bsl[64*72];
    int t = threadIdx.x;
    int l = t & 63, w = t >> 6;
    int wr = w >> 1, wc = w & 1;
    int r0 = blockIdx.y*64, c0 = blockIdx.x*64;
    f32x4 acc[2][2];
#pragma unroll
    for (int i = 0; i < 2; ++i)
#pragma unroll
        for (int j = 0; j < 2; ++j) acc[i][j] = (f32x4){0.f,0.f,0.f,0.f};
    int arow = wr*32 + (l & 15);
    int brow = wc*32 + (l & 15);
    int koff = (l >> 4)*8;
    const float* sbase = xscp + ((c0 >> 6) << 10);   // per-(b,n) x scales, b = c0/64
    for (int k0 = kbase; k0 < kbase + 512; k0 += 64) {
        __syncthreads();
        // A tiles: coalesced f16x8
#pragma unroll
        for (int c = 0; c < 2; ++c) {
            int id = t + 256*c;
            int row = id >> 3, k8 = id & 7;
            *(f16x8*)(&Ash[row*72 + k8*8]) =
                *(const f16x8*)(&Ahi[(size_t)(r0+row)*1024 + k0 + k8*8]);
            *(f16x8*)(&Asl[row*72 + k8*8]) =
                *(const f16x8*)(&Alo[(size_t)(r0+row)*1024 + k0 + k8*8]);
        }
        // B tile from transposed source, coalesced along m
        if (job == 1) {
#pragma unroll
            for (int c = 0; c < 2; ++c) {
                int id = t + 256*c;
                int row = id >> 3, k8 = id & 7;
                short8_t q8 = *(const short8_t*)(xqTp + (size_t)(c0+row)*1024 + k0 + k8*8);
                float4 s0 = *(const float4*)(sbase + k0 + k8*8);
                float4 s1 = *(const float4*)(sbase + k0 + k8*8 + 4);
                float vv[8];
                vv[0] = (float)q8[0]*s0.x; vv[1] = (float)q8[1]*s0.y;
                vv[2] = (float)q8[2]*s0.z; vv[3] = (float)q8[3]*s0.w;
                vv[4] = (float)q8[4]*s1.x; vv[5] = (float)q8[5]*s1.y;
                vv[6] = (float)q8[6]*s1.z; vv[7] = (float)q8[7]*s1.w;
                f16x8 hi, lo;
#pragma unroll
                for (int i = 0; i < 8; ++i) {
                    _Float16 h = (_Float16)vv[i];
                    hi[i] = h;
                    lo[i] = (_Float16)(vv[i] - (float)h);
                }
                *(f16x8*)(&Bsh[row*72 + k8*8]) = hi;
                *(f16x8*)(&Bsl[row*72 + k8*8]) = lo;
            }
        } else {
#pragma unroll
            for (int c = 0; c < 4; ++c) {
                int id = t + 256*c;
                int row = id >> 4, kq = id & 15;
                float4 v = *(const float4*)(&BTf[(size_t)(c0+row)*1024 + k0 + kq*4]);
                float vv[4] = {v.x, v.y, v.z, v.w};
                f16x4 hi, lo;
#pragma unroll
                for (int i = 0; i < 4; ++i) {
                    _Float16 h = (_Float16)vv[i];
                    hi[i] = h;
                    lo[i] = (_Float16)(vv[i] - (float)h);
                }
                *(f16x4*)(&Bsh[row*72 + kq*4]) = hi;
                *(f16x4*)(&Bsl[row*72 + kq*4]) = lo;
            }
        }
        __syncthreads();
#pragma unroll
        for (int kk = 0; kk < 2; ++kk) {
            int ko = kk*32 + koff;
            f16x8 ah0 = *(const f16x8*)(&Ash[(size_t)arow*72 + ko]);
            f16x8 ah1 = *(const f16x8*)(&Ash[(size_t)(arow+16)*72 + ko]);
            f16x8 al0 = *(const f16x8*)(&Asl[(size_t)arow*72 + ko]);
            f16x8 al1 = *(const f16x8*)(&Asl[(size_t)(arow+16)*72 + ko]);
            f16x8 bh0 = *(const f16x8*)(&Bsh[(size_t)brow*72 + ko]);
            f16x8 bh1 = *(const f16x8*)(&Bsh[(size_t)(brow+16)*72 + ko]);
            f16x8 bl0 = *(const f16x8*)(&Bsl[(size_t)brow*72 + ko]);
            f16x8 bl1 = *(const f16x8*)(&Bsl[(size_t)(brow+16)*72 + ko]);
            acc[0][0] = __builtin_amdgcn_mfma_f32_16x16x32_f16(al0, bh0, acc[0][0], 0, 0, 0);
            acc[0][0] = __builtin_amdgcn_mfma_f32_16x16x32_f16(ah0, bl0, acc[0][0], 0, 0, 0);
            acc[0][0] = __builtin_amdgcn_mfma_f32_16x16x32_f16(ah0, bh0, acc[0][0], 0, 0, 0);
            acc[0][1] = __builtin_amdgcn_mfma_f32_16x16x32_f16(al0, bh1, acc[0][1], 0, 0, 0);
            acc[0][1] = __builtin_amdgcn_mfma_f32_16x16x32_f16(ah0, bl1, acc[0][1], 0, 0, 0);
            acc[0][1] = __builtin_amdgcn_mfma_f32_16x16x32_f16(ah0, bh1, acc[0][1], 0, 0, 0);
            acc[1][0] = __builtin_amdgcn_mfma_f32_16x16x32_f16(al1, bh0, acc[1][0], 0, 0, 0);
            acc[1][0] = __builtin_amdgcn_mfma_f32_16x16x32_f16(ah1, bl0, acc[1][0], 0, 0, 0);
            acc[1][0] = __builtin_amdgcn_mfma_f32_16x16x32_f16(ah1, bh0, acc[1][0], 0, 0, 0);
            acc[1][1] = __builtin_amdgcn_mfma_f32_16x16x32_f16(al1, bh1, acc[1][1], 0, 0, 0);
            acc[1][1] = __builtin_amdgcn_mfma_f32_16x16x32_f16(ah1, bl1, acc[1][1], 0, 0, 0);
            acc[1][1] = __builtin_amdgcn_mfma_f32_16x16x32_f16(ah1, bh1, acc[1][1], 0, 0, 0);
        }
    }
    // C/D layout: col = lane&15, row = 4*(lane>>4)+reg  [measured m89/m91]
#pragma unroll
    for (int fr = 0; fr < 2; ++fr)
#pragma unroll
        for (int fc = 0; fc < 2; ++fc) {
            int orow = r0 + wr*32 + fr*16 + ((l >> 4) << 2);
            int ocol = c0 + wc*32 + fc*16 + (l & 15);
#pragma unroll
            for (int i = 0; i < 4; ++i)
                out[(size_t)(orow+i)*1024 + ocol] = acc[fr][fc][i];
        }
}

// zr[n][b][o] = sigmoid([x,h,Ax,Ah]·Wq[n](o,:)·ws + bg); writes zhT[j][n]=z*h.
// blockIdx XCD-swizzled so consecutive-n blocks share an XCD (scatter-write locality).
template<int FIRST>
__global__ __launch_bounds__(256) void gate_k(
    const short* __restrict__ xqTp, const float* __restrict__ xscp,
    const float* __restrict__ hst, const float* __restrict__ pAx,
    const float* __restrict__ pAh, const short* __restrict__ WQ,
    const float* __restrict__ wsc, const float* __restrict__ bg,
    float* __restrict__ zr, float* __restrict__ zhT)
{
    __shared__ float inp[16*256];
    int n = ((blockIdx.x & 7) << 7) | (blockIdx.x >> 3);
    int t = threadIdx.x;
    size_t nb = (size_t)n*1024;
    for (int i = t; i < 1024; i += 256) {
        int b = i >> 6, c = i & 63;
        float sx = xscp[(b << 10) + n];
        inp[b*256 + c]       = (float)xqTp[(size_t)i*1024 + n] * sx;
        inp[b*256 + 64 + c]  = FIRST ? 0.f : hst[nb + i];
        inp[b*256 + 128 + c] = pAx[nb + i] + pAx[nb + i + 1048576];
        inp[b*256 + 192 + c] = FIRST ? 0.f : (pAh[nb + i] + pAh[nb + i + 1048576]);
    }
    __syncthreads();
    int o = t & 127, g = t >> 7;
    const short* wp = WQ + ((size_t)n*128 + o)*256;
    float ws = wsc[n*128 + o];
    float bias = bg[n*128 + o];
    float acc[8];
#pragma unroll
    for (int u = 0; u < 8; ++u) acc[u] = 0.f;
    for (int k0 = 0; k0 < 256; k0 += 4) {
        short4_t w4 = *(const short4_t*)(wp + k0);
        float w0 = (float)w4.x, w1 = (float)w4.y, w2 = (float)w4.z, w3 = (float)w4.w;
#pragma unroll
        for (int u = 0; u < 8; ++u) {
            float4 iv = *(const float4*)(&inp[(g*8 + u)*256 + k0]);
            acc[u] += w0*iv.x + w1*iv.y + w2*iv.z + w3*iv.w;
        }
    }
#pragma unroll
    for (int u = 0; u < 8; ++u) {
        int b = g*8 + u;
        float pre = acc[u]*ws + bias;
        float val = 1.f/(1.f + expf(-pre));
        zr[((size_t)n*16 + b)*128 + o] = val;
        if (!FIRST && o < 64)
            zhT[(size_t)(b*64 + o)*1024 + n] = val * inp[b*256 + 64 + o];
    }
}

// h_new = r*h + (1-r)*tanh([x, z*h, Ax, Azh]·Wu[n]·ws + bu); writes hst rows,
// hT columns, (WX) next-layer xqT i16 columns. XCD-swizzled blockIdx.
template<int FIRST, int WX>
__global__ __launch_bounds__(256) void upd_k(
    short* __restrict__ xqTp, const float* __restrict__ xscp,
    float* __restrict__ hst, const float* __restrict__ pAx,
    const float* __restrict__ pAzh, const float* __restrict__ zr,
    const short* __restrict__ WQ, const float* __restrict__ wsc,
    const float* __restrict__ bu, float* __restrict__ hT)
{
    __shared__ float inp[16*256];
    int n = ((blockIdx.x & 7) << 7) | (blockIdx.x >> 3);
    int t = threadIdx.x;
    size_t nb = (size_t)n*1024;
    for (int i = t; i < 1024; i += 256) {
        int b = i >> 6, c = i & 63;
        float sx = xscp[(b << 10) + n];
        float hv = FIRST ? 0.f : hst[nb + i];
        float zv = zr[((size_t)n*16 + b)*128 + c];
        inp[b*256 + c]       = (float)xqTp[(size_t)i*1024 + n] * sx;
        inp[b*256 + 64 + c]  = zv * hv;
        inp[b*256 + 128 + c] = pAx[nb + i] + pAx[nb + i + 1048576];
        inp[b*256 + 192 + c] = FIRST ? 0.f : (pAzh[nb + i] + pAzh[nb + i + 1048576]);
    }
    __syncthreads();
    int o = t & 63, g = t >> 6;
    const short* wp = WQ + ((size_t)n*64 + o)*256;
    float ws = wsc[n*64 + o];
    float bias = bu[n*64 + o];
    float acc[4];
#pragma unroll
    for (int u = 0; u < 4; ++u) acc[u] = 0.f;
    for (int k0 = 0; k0 < 256; k0 += 4) {
        short4_t w4 = *(const short4_t*)(wp + k0);
        float w0 = (float)w4.x, w1 = (float)w4.y, w2 = (float)w4.z, w3 = (float)w4.w;
#pragma unroll
        for (int u = 0; u < 4; ++u) {
            float4 iv = *(const float4*)(&inp[(g*4 + u)*256 + k0]);
            acc[u] += w0*iv.x + w1*iv.y + w2*iv.z + w3*iv.w;
        }
    }
#pragma unroll
    for (int u = 0; u < 4; ++u) {
        int b = g*4 + u;
        float r = zr[((size_t)n*16 + b)*128 + 64 + o];
        float hold = FIRST ? 0.f : hst[nb + b*64 + o];
        float hc = tanhf(acc[u]*ws + bias);
        float hn = r*hold + (1.f - r)*hc;
        hst[nb + b*64 + o] = hn;
        hT[(size_t)(b*64 + o)*1024 + n] = hn;
        if (WX) xqTp[(size_t)(b*64 + o)*1024 + n] = (short)__float2int_rn(hn*32767.f);
    }
}

// out[b][o][n] = h[n][b][:]·ecw[o][:] + ecb[o]
__global__ __launch_bounds__(256) void endconv_k(
    const float* __restrict__ hst, const float* __restrict__ ecw,
    const float* __restrict__ ecb, float* __restrict__ out)
{
    int idx = blockIdx.x*256 + threadIdx.x;
    int n = idx & 1023;
    int o = (idx >> 10) % HOR;
    int b = idx / (HOR*1024);
    float s = ecb[o];
#pragma unroll
    for (int hh = 0; hh < 64; ++hh)
        s += hst[((size_t)n*16 + b)*64 + hh] * ecw[o*64 + hh];
    out[idx] = s;
}

extern "C" void kernel_launch(void* const* d_in, const int* in_sizes, int n_in,
                              void* d_out, int out_size, void* d_ws, size_t ws_size,
                              hipStream_t stream)
{
    const float* source = (const float*)d_in[0];
    const float* emb    = (const float*)d_in[2];
    const float* vw     = (const float*)d_in[3];
    const float* gate_w = (const float*)d_in[4];
    const float* gate_b = (const float*)d_in[5];
    const float* upd_w  = (const float*)d_in[6];
    const float* upd_b  = (const float*)d_in[7];
    const float* ecw    = (const float*)d_in[8];
    const float* ecb    = (const float*)d_in[9];
    float* out = (float*)d_out;

    // ---- workspace carve: ~197 MB ----
    char* p = (char*)d_ws;
    _Float16* Ahi = (_Float16*)p; p += (size_t)1048576*2;    //   2.0 MB
    _Float16* Alo = (_Float16*)p; p += (size_t)1048576*2;    //   2.0 MB
    short* WgQ  = (short*)p;  p += (size_t)33554432*2;       //  64.0 MB
    short* WuQ  = (short*)p;  p += (size_t)16777216*2;       //  32.0 MB
    float* swg  = (float*)p;  p += (size_t)131072*4;         //   0.5 MB
    float* swu  = (float*)p;  p += (size_t)65536*4;          //   0.25 MB
    float* bgn  = (float*)p;  p += (size_t)131072*4;         //   0.5 MB
    float* bun  = (float*)p;  p += (size_t)65536*4;          //   0.25 MB
    short* xqT  = (short*)p;  p += (size_t)25165824*2;       //  48.0 MB  [p][j][n] i16
    float* xscA = (float*)p;  p += (size_t)393216*4;         //   1.5 MB  layer-0 scales [p][b][n]
    float* xscB = (float*)p;  p += (size_t)393216*4;         //   1.5 MB  layer-1 scales (const)
    float* hbuf = (float*)p;  p += (size_t)1048576*4;        //   4.0 MB  h rows [n][j]
    float* hT   = (float*)p;  p += (size_t)1048576*4;        //   4.0 MB  h cols [j][n]
    float* zrb  = (float*)p;  p += (size_t)2097152*4;        //   8.0 MB
    float* zhT  = (float*)p;  p += (size_t)1048576*4;        //   4.0 MB  (z*h)^T
    float* pAh  = (float*)p;  p += (size_t)2097152*4;        //   8.0 MB  split-K pair
    float* pAx  = (float*)p;  p += (size_t)2097152*4;        //   8.0 MB  split-K pair
    float* pAzh = (float*)p;  p += (size_t)2097152*4;        //   8.0 MB  split-K pair
    float* gwT  = pAzh;   // 2 MB scratch, aliases pAzh (dead during layer setup)

    embedq4_k<<<dim3(16,24), 256, 0, stream>>>(source, vw, xqT, xscA);
    adj_k<<<1024, 256, 0, stream>>>(emb, Ahi, Alo);
    fill_k<<<1536, 256, 0, stream>>>(xscB, 1.f/32767.f, 393216);

    for (int l = 0; l < 2; ++l) {
        const float* xsc2 = (l == 0) ? xscA : xscB;
        wtrans_k<128><<<2048, 256, 0, stream>>>(gate_w + (size_t)l*524288, gwT);
        wnodeq2_k<128><<<dim3(256,4), 256, 0, stream>>>(emb, gwT, WgQ, swg);
        wtrans_k<64><<<1024, 256, 0, stream>>>(upd_w + (size_t)l*262144, gwT);
        wnodeq2_k<64><<<dim3(256,4), 256, 0, stream>>>(emb, gwT, WuQ, swu);
        bias_k<<<512, 256, 0, stream>>>(emb, gate_b + l*2048, bgn, 128);
        bias_k<<<256, 256, 0, stream>>>(emb, upd_b + l*1024, bun, 64);
        for (int ps = 0; ps < PWIN; ++ps) {
            short* xqT_p = xqT + ((size_t)ps << 20);
            const float* xsc_p = xsc2 + (size_t)ps*16384;
            if (ps == 0) {
                // h == 0: only A@x needed (job 1, both K-halves)
                gemm16_k<<<dim3(16,16,2), 256, 0, stream>>>(Ahi, Alo, hT, xqT_p, xsc_p, zhT, pAh, pAx, pAzh, 2);
                gate_k<1><<<1024, 256, 0, stream>>>(xqT_p, xsc_p, hbuf, pAx, pAh, WgQ, swg, bgn, zrb, zhT);
                if (l == 0)
                    upd_k<1,1><<<1024, 256, 0, stream>>>(xqT_p, xsc_p, hbuf, pAx, pAzh, zrb, WuQ, swu, bun, hT);
                else
                    upd_k<1,0><<<1024, 256, 0, stream>>>(xqT_p, xsc_p, hbuf, pAx, pAzh, zrb, WuQ, swu, bun, hT);
            } else {
                gemm16_k<<<dim3(16,16,4), 256, 0, stream>>>(Ahi, Alo, hT, xqT_p, xsc_p, zhT, pAh, pAx, pAzh, 0);
                gate_k<0><<<1024, 256, 0, stream>>>(xqT_p, xsc_p, hbuf, pAx, pAh, WgQ, swg, bgn, zrb, zhT);
                gemm16_k<<<dim3(16,16,2), 256, 0, stream>>>(Ahi, Alo, hT, xqT_p, xsc_p, zhT, pAh, pAx, pAzh, 4);
                if (l == 0)
                    upd_k<0,1><<<1024, 256, 0, stream>>>(xqT_p, xsc_p, hbuf, pAx, pAzh, zrb, WuQ, swu, bun, hT);
                else
                    upd_k<0,0><<<1024, 256, 0, stream>>>(xqT_p, xsc_p, hbuf, pAx, pAzh, zrb, WuQ, swu, bun, hT);
            }
        }
    }
    endconv_k<<<768, 256, 0, stream>>>(hbuf, ecw, ecb, out);
}